// Round 6
// baseline (207.697 us; speedup 1.0000x reference)
//
#include <hip/hip_runtime.h>

// MEASUREMENT ROUND: identical to round 5, but stage1 is launched TWICE
// (idempotent, writes identical partials). dur_us delta vs round 5 (186.3 us)
// = stage1's duration, which the top-5 counter table cannot show (it's fully
// occupied by >=74us d_ws-poison fills). This decides whether stage1 has
// ~20us of headroom left or whether we're at the harness-dominated floor.

constexpr int C_COLS        = 1000;
constexpr int ROW_BYTES     = 4000;
constexpr int ROWS_PER_BLK  = 8;
constexpr int BLOCK_BYTES   = 32000;   // 8 rows * 4000 B, 16B-aligned
constexpr int CHUNK         = 1024;    // one global_load_lds: 64 lanes * 16 B

typedef __attribute__((address_space(3))) void        lds_void_t;
typedef __attribute__((address_space(1))) const void  gbl_void_t;

__global__ __launch_bounds__(256) void hloss_stage1(
    const float* __restrict__ outputs,
    const int*   __restrict__ target,
    float* __restrict__ partials)
{
    __shared__ __align__(16) char smem[BLOCK_BYTES];
    __shared__ float part[4];

    const int wave = threadIdx.x >> 6;          // 4 waves / block
    const int lane = threadIdx.x & 63;

    const char* gbase = (const char*)outputs + (size_t)blockIdx.x * BLOCK_BYTES;

#pragma unroll
    for (int j = 0; j < 8; ++j) {
        const int chunk = wave * 8 + j;
        const int off   = chunk * CHUNK;
        if (off + lane * 16 < BLOCK_BYTES) {
            __builtin_amdgcn_global_load_lds(
                (gbl_void_t*)(gbase + off + (size_t)lane * 16),
                (lds_void_t*)(smem + off),
                16, 0, 0);
        }
    }

    const int row0 = blockIdx.x * ROWS_PER_BLK + wave * 2;
    const int t0 = target[row0];
    const int t1 = target[row0 + 1];

    __syncthreads();   // drains vmcnt -> all LDS bytes valid

    float lw = 0.f;
#pragma unroll
    for (int r = 0; r < 2; ++r) {
        const int t    = r ? t1 : t0;
        const int f100 = (t / 100) * 25;
        const int lo10 = (t / 10) * 10;
        const float*  rowp = (const float*)(smem + (wave * 2 + r) * ROW_BYTES);
        const float4* rp   = (const float4*)rowp;
#pragma unroll
        for (int k = 0; k < 4; ++k) {
            const int f = (k << 6) + lane;
            if (f < 250) {
                const float4 v  = rp[f];
                const float  s4 = (v.x + v.y) + (v.z + v.w);
                const float  w  = ((unsigned)(f - f100) < 25u) ? 0.75f : 0.5f;
                lw = fmaf(s4, w, lw);
            }
        }
        if (lane < 11) {
            const int col = (lane < 10) ? (lo10 + lane) : t;
            lw = fmaf(0.125f, rowp[col], lw);
        }
    }

#pragma unroll
    for (int off = 32; off >= 1; off >>= 1) {
        lw += __shfl_xor(lw, off, 64);
    }

    if (lane == 0) part[wave] = lw;
    __syncthreads();
    if (threadIdx.x == 0) {
        partials[blockIdx.x] = (part[0] + part[1]) + (part[2] + part[3]);
    }
}

__global__ __launch_bounds__(256) void hloss_stage2(
    const float* __restrict__ partials,
    float* __restrict__ out,
    int n_f4, float Bf)
{
    const int lane = threadIdx.x & 63;
    const int wave = threadIdx.x >> 6;
    const float4* p = reinterpret_cast<const float4*>(partials);

    float s = 0.f;
    for (int i = threadIdx.x; i < n_f4; i += 256) {
        const float4 v = p[i];
        s += (v.x + v.y) + (v.z + v.w);
    }
#pragma unroll
    for (int off = 32; off >= 1; off >>= 1) {
        s += __shfl_xor(s, off, 64);
    }
    __shared__ float part[4];
    if (lane == 0) part[wave] = s;
    __syncthreads();
    if (threadIdx.x == 0) {
        out[0] = Bf - ((part[0] + part[1]) + (part[2] + part[3]));
    }
}

extern "C" void kernel_launch(void* const* d_in, const int* in_sizes, int n_in,
                              void* d_out, int out_size, void* d_ws, size_t ws_size,
                              hipStream_t stream)
{
    const float* outputs  = (const float*)d_in[0];
    const int*   target   = (const int*)d_in[1];
    float*       loss     = (float*)d_out;
    float*       partials = (float*)d_ws;

    const int B = in_sizes[1];                  // 32768 rows
    const int nblocks = B / ROWS_PER_BLK;       // 4096 blocks

    // Launched twice on purpose: idempotent; the dur_us delta vs round 5
    // measures stage1's duration (see header comment).
    hloss_stage1<<<nblocks, 256, 0, stream>>>(outputs, target, partials);
    hloss_stage1<<<nblocks, 256, 0, stream>>>(outputs, target, partials);
    hloss_stage2<<<1, 256, 0, stream>>>(partials, loss, nblocks / 4, (float)B);
}

// Round 7
// 185.172 us; speedup vs baseline: 1.1216x; 1.1216x over previous
//
#include <hip/hip_runtime.h>

// Hierarchical loss. Per-row:
//   win = 0.5*rowsum + 0.25*(100-block) + 0.125*(10-block) + 0.125*out[t]
//   loss = B - sum(win)
// FINAL structure (round-6 measurement: stage1 = 21.4 us = 6.13 TB/s on
// 131 MB read = 97% of the ~6.3 TB/s achievable ceiling -> memory-bound
// floor reached). Stage1: global_load_lds DMA staging of 8 contiguous
// rows/block into LDS, weighted reduce, one partial per block. Stage2:
// single-block reduce of 4096 partials -> loss = B - sum.

constexpr int C_COLS        = 1000;
constexpr int ROW_BYTES     = 4000;
constexpr int ROWS_PER_BLK  = 8;
constexpr int BLOCK_BYTES   = 32000;   // 8 rows * 4000 B, 16B-aligned
constexpr int CHUNK         = 1024;    // one global_load_lds: 64 lanes * 16 B

typedef __attribute__((address_space(3))) void        lds_void_t;
typedef __attribute__((address_space(1))) const void  gbl_void_t;

__global__ __launch_bounds__(256) void hloss_stage1(
    const float* __restrict__ outputs,
    const int*   __restrict__ target,
    float* __restrict__ partials)
{
    __shared__ __align__(16) char smem[BLOCK_BYTES];
    __shared__ float part[4];

    const int wave = threadIdx.x >> 6;          // 4 waves / block
    const int lane = threadIdx.x & 63;

    const char* gbase = (const char*)outputs + (size_t)blockIdx.x * BLOCK_BYTES;

    // Stage 32000 B into LDS: 32 chunks (31 full + 1 with 16 lanes), 8/wave.
    // LDS dest is wave-uniform base + lane*16 -> flat layout matches the
    // contiguous global rows exactly (no padding allowed, m104 semantics).
#pragma unroll
    for (int j = 0; j < 8; ++j) {
        const int chunk = wave * 8 + j;
        const int off   = chunk * CHUNK;
        if (off + lane * 16 < BLOCK_BYTES) {
            __builtin_amdgcn_global_load_lds(
                (gbl_void_t*)(gbase + off + (size_t)lane * 16),
                (lds_void_t*)(smem + off),
                16, 0, 0);
        }
    }

    const int row0 = blockIdx.x * ROWS_PER_BLK + wave * 2;
    const int t0 = target[row0];
    const int t1 = target[row0 + 1];

    __syncthreads();   // drains vmcnt -> all LDS bytes valid

    // Reduce 2 rows per wave from LDS. 100-block is float4-aligned
    // (100 = 25 x float4): one FMA per float4 with w = in-block ? .75 : .5;
    // unaligned 10-block + target element are an 11-lane LDS tail.
    float lw = 0.f;
#pragma unroll
    for (int r = 0; r < 2; ++r) {
        const int t    = r ? t1 : t0;
        const int f100 = (t / 100) * 25;
        const int lo10 = (t / 10) * 10;
        const float*  rowp = (const float*)(smem + (wave * 2 + r) * ROW_BYTES);
        const float4* rp   = (const float4*)rowp;
#pragma unroll
        for (int k = 0; k < 4; ++k) {
            const int f = (k << 6) + lane;
            if (f < 250) {
                const float4 v  = rp[f];
                const float  s4 = (v.x + v.y) + (v.z + v.w);
                const float  w  = ((unsigned)(f - f100) < 25u) ? 0.75f : 0.5f;
                lw = fmaf(s4, w, lw);
            }
        }
        if (lane < 11) {
            const int col = (lane < 10) ? (lo10 + lane) : t;
            lw = fmaf(0.125f, rowp[col], lw);
        }
    }

#pragma unroll
    for (int off = 32; off >= 1; off >>= 1) {
        lw += __shfl_xor(lw, off, 64);
    }

    if (lane == 0) part[wave] = lw;
    __syncthreads();
    if (threadIdx.x == 0) {
        partials[blockIdx.x] = (part[0] + part[1]) + (part[2] + part[3]);
    }
}

// Reduce 4096 partials -> out[0] = Bf - sum
__global__ __launch_bounds__(256) void hloss_stage2(
    const float* __restrict__ partials,
    float* __restrict__ out,
    int n_f4, float Bf)
{
    const int lane = threadIdx.x & 63;
    const int wave = threadIdx.x >> 6;
    const float4* p = reinterpret_cast<const float4*>(partials);

    float s = 0.f;
    for (int i = threadIdx.x; i < n_f4; i += 256) {
        const float4 v = p[i];
        s += (v.x + v.y) + (v.z + v.w);
    }
#pragma unroll
    for (int off = 32; off >= 1; off >>= 1) {
        s += __shfl_xor(s, off, 64);
    }
    __shared__ float part[4];
    if (lane == 0) part[wave] = s;
    __syncthreads();
    if (threadIdx.x == 0) {
        out[0] = Bf - ((part[0] + part[1]) + (part[2] + part[3]));
    }
}

extern "C" void kernel_launch(void* const* d_in, const int* in_sizes, int n_in,
                              void* d_out, int out_size, void* d_ws, size_t ws_size,
                              hipStream_t stream)
{
    const float* outputs  = (const float*)d_in[0];
    const int*   target   = (const int*)d_in[1];
    float*       loss     = (float*)d_out;
    float*       partials = (float*)d_ws;

    const int B = in_sizes[1];                  // 32768 rows
    const int nblocks = B / ROWS_PER_BLK;       // 4096 blocks

    hloss_stage1<<<nblocks, 256, 0, stream>>>(outputs, target, partials);
    hloss_stage2<<<1, 256, 0, stream>>>(partials, loss, nblocks / 4, (float)B);
}